// Round 8
// baseline (676.381 us; speedup 1.0000x reference)
//
#include <hip/hip_runtime.h>

// B=32768 rows, C=4096 cols, f32.
// Kernel 1: one BLOCK (4 waves, 256 thr) per row. Each lane holds 4 x float4
//   (16 data VGPRs -> high occupancy, short per-row serial chain).
//   Layout: thread tid owns float4 chunks c = it*256+tid, it=0..3 (coalesced).
//   pass1: max+argmax (regs -> shfl -> 4-entry LDS combine),
//   pass2: sum exp(v-m) (regs -> shfl -> LDS). x_t extracted in-register by
//   the owning thread, broadcast via LDS. Thread 0 writes ce*w to ws[row].
// Kernel 2: one block reduces 32768 partials -> mean -> d_out[0].

#define NROWS 32768
#define NCOLS 4096

typedef float f32x4 __attribute__((ext_vector_type(4)));

__global__ __launch_bounds__(256) void wl_rows_kernel(
    const float* __restrict__ logits,
    const int* __restrict__ target,
    const float* __restrict__ weights,
    float* __restrict__ partial) {
  const int tid = threadIdx.x;
  const int lane = tid & 63;
  const int wid = tid >> 6;
  const int row = blockIdx.x;
  const float* rowp = logits + (size_t)row * NCOLS;

  __shared__ float ls_val[4];
  __shared__ int ls_idx[4];
  __shared__ float ls_sum[4];
  __shared__ float ls_xt;

  const int t = target[row];        // block-uniform
  const int tchunk = t >> 2;        // float4 chunk index 0..1023
  const int towner = tchunk & 255;  // owning tid (chunk c = it*256 + tid)
  const int tit = tchunk >> 8;      // which it
  const int tcomp = t & 3;          // component

  // ---- load row: 256 thr x 4 float4, coalesced, non-temporal ----
  f32x4 v[4];
#pragma unroll
  for (int it = 0; it < 4; ++it) {
    v[it] = __builtin_nontemporal_load(
        reinterpret_cast<const f32x4*>(rowp + (it * 256 + tid) * 4));
  }

  // ---- x_t: owning thread extracts (compile-time index), stashes in LDS ----
  if (tid == towner) {
    float cand = 0.f;
#pragma unroll
    for (int it = 0; it < 4; ++it) {
      if (it == tit) {
        const float a = (tcomp & 1) ? v[it].y : v[it].x;
        const float b = (tcomp & 1) ? v[it].w : v[it].z;
        cand = (tcomp & 2) ? b : a;
      }
    }
    ls_xt = cand;
  }

  // ---- pass 1: thread-local max + argmax (indices ascend -> '>' keeps first) ----
  float bv = v[0].x;
  int bi = tid * 4;  // global elem idx of v[0].x = (0*256+tid)*4
#pragma unroll
  for (int it = 0; it < 4; ++it) {
    const int base = (it * 256 + tid) * 4;
    if (v[it].x > bv) { bv = v[it].x; bi = base + 0; }
    if (v[it].y > bv) { bv = v[it].y; bi = base + 1; }
    if (v[it].z > bv) { bv = v[it].z; bi = base + 2; }
    if (v[it].w > bv) { bv = v[it].w; bi = base + 3; }
  }
  // wave reduce (max, first-index tiebreak)
#pragma unroll
  for (int off = 32; off > 0; off >>= 1) {
    float ov = __shfl_xor(bv, off, 64);
    int oi = __shfl_xor(bi, off, 64);
    if (ov > bv || (ov == bv && oi < bi)) { bv = ov; bi = oi; }
  }
  if (lane == 0) { ls_val[wid] = bv; ls_idx[wid] = bi; }
  __syncthreads();
  // combine 4 wave results (uniform across block)
  bv = ls_val[0];
  bi = ls_idx[0];
#pragma unroll
  for (int w = 1; w < 4; ++w) {
    const float ov = ls_val[w];
    const int oi = ls_idx[w];
    if (ov > bv || (ov == bv && oi < bi)) { bv = ov; bi = oi; }
  }
  // bv = row max m, bi = argmax (first occurrence)

  // ---- pass 2: sum of exp(v - m) ----
  float s = 0.f;
#pragma unroll
  for (int it = 0; it < 4; ++it) {
    s += __expf(v[it].x - bv);
    s += __expf(v[it].y - bv);
    s += __expf(v[it].z - bv);
    s += __expf(v[it].w - bv);
  }
#pragma unroll
  for (int off = 32; off > 0; off >>= 1) s += __shfl_xor(s, off, 64);
  if (lane == 0) ls_sum[wid] = s;
  __syncthreads();

  // ---- thread 0: ce = m + log(sumexp) - x_t ; w = weights[t][pred] ----
  if (tid == 0) {
    const float st = ls_sum[0] + ls_sum[1] + ls_sum[2] + ls_sum[3];
    const float w = weights[(size_t)t * NCOLS + bi];
    const float ce = bv + __logf(st) - ls_xt;
    partial[row] = ce * w;
  }
}

__global__ __launch_bounds__(1024) void wl_reduce_kernel(
    const float* __restrict__ partial, float* __restrict__ out) {
  __shared__ float wsum[16];
  const int tid = threadIdx.x;
  float s = 0.f;
  const f32x4* p4 = reinterpret_cast<const f32x4*>(partial);
#pragma unroll
  for (int i = 0; i < 8; ++i) {  // 8192 float4 total / 1024 threads
    f32x4 p = p4[tid + i * 1024];
    s += p.x + p.y + p.z + p.w;
  }
#pragma unroll
  for (int off = 32; off > 0; off >>= 1) s += __shfl_xor(s, off, 64);
  if ((tid & 63) == 0) wsum[tid >> 6] = s;
  __syncthreads();
  if (tid < 16) {
    s = wsum[tid];
#pragma unroll
    for (int off = 8; off > 0; off >>= 1) s += __shfl_xor(s, off, 64);
    if (tid == 0) out[0] = s * (1.0f / NROWS);
  }
}

extern "C" void kernel_launch(void* const* d_in, const int* in_sizes, int n_in,
                              void* d_out, int out_size, void* d_ws, size_t ws_size,
                              hipStream_t stream) {
  const float* logits = (const float*)d_in[0];
  const int* target = (const int*)d_in[1];
  const float* weights = (const float*)d_in[2];
  float* partial = (float*)d_ws;  // 32768 floats = 128 KiB
  float* out = (float*)d_out;

  wl_rows_kernel<<<NROWS, 256, 0, stream>>>(logits, target, weights, partial);
  wl_reduce_kernel<<<1, 1024, 0, stream>>>(partial, out);
}